// Round 5
// baseline (4924.225 us; speedup 1.0000x reference)
//
#include <hip/hip_runtime.h>
#include <hip/hip_cooperative_groups.h>

// MAC network forward, restructured:
//  - inter2 GEMM (34 GMAC/step) algebraically collapsed via linearity of the
//    r_att contraction: r_att[b,k] = sum_j knowledge[b,j,k]*g[b,j],
//    g = mem_p * h[:, :D] + h[:, D:],  h = (new_control*ra_w) @ ri_w.
//  - q_pa part of control-unit GEMM hoisted out of the step loop (qc_all).
//  - ca_b / ra_b / ri_b are per-row constants under softmax -> dropped.
// All fp32.
//
// R5:
//  - gemm_wide reverted to R3 exact config (256 thr, launch_bounds(256,2)).
//    Empirical launch_bounds model from R1/R3/R4 counters: VGPR cap ~
//    256/secondArg regardless of block size; arg=4 caps at 64 -> spill.
//  - The 12-step loop (72 small dependent dispatches, ~20us each vs ~30us
//    traffic floor PER STEP) moved into ONE persistent cooperative kernel:
//    256 blocks x 512 thr (1 block/CU guaranteed co-resident), 7 phases per
//    step separated by grid.sync(). Phase bodies are ports of the proven
//    standalone kernels.

#define NSTEP 12

namespace cg = cooperative_groups;

struct GemmArgs {
  const float* X1; long x1g;   // [32, c1], per-group stride
  const float* X2; long x2g;   // [32, c2] or null (concat second half)
  int c1, c2;
  const float* W; int ldw; long wg;      // W[N, C] row-major (out = X @ W.T)
  const float* bias; long biasg;         // len N or null
  const float* addend; long addg;        // [32, N] or null
  const float* xscale;                   // len C or null (elementwise on X)
  float* out; long outg;                 // [32, N]
  int N;
};

__device__ __forceinline__ void gload_lds16(const float* g, float* l) {
  __builtin_amdgcn_global_load_lds(
      (const __attribute__((address_space(1))) void*)g,
      (__attribute__((address_space(3))) void*)l, 16, 0, 0);
}

// Streaming thin-M GEMM for large W (pa, qc). X1-only (no concat/xscale).
// R3-proven: 256 thr = 4 waves, 8-col x 32-row output tile, X staged via
// global_load_lds into double-buffered 32KB chunks, W regs prefetched one
// chunk ahead. VGPR 112, no spill, 66us on the 96MB pa stream.
__global__ __launch_bounds__(256, 2) void gemm_wide_kernel(GemmArgs a) {
  __shared__ float xs[2][32 * 256];  // 2 x 32 KB
  const int g = blockIdx.y;
  const int C = a.c1;
  const int nc = C >> 8;  // chunks of 256 columns (C % 256 == 0)
  const float* X1 = a.X1 + (long)g * a.x1g;
  const float* W = a.W + (long)g * a.wg;
  const int wave = threadIdx.x >> 6;
  const int lane = threadIdx.x & 63;
  const int n0 = blockIdx.x * 8 + (wave >> 1) * 4;
  const int bh = (wave & 1) * 16;
  const float* wrow = W + (long)n0 * a.ldw;
  const int cl = lane * 4;

  float acc[64];
#pragma unroll
  for (int v = 0; v < 64; v++) acc[v] = 0.f;

  auto stage = [&](int buf, int c0) {
#pragma unroll
    for (int r = 0; r < 8; r++) {
      int idx = threadIdx.x + 256 * r;
      int b = idx >> 6;
      gload_lds16(X1 + (long)b * C + c0 + (idx & 63) * 4, &xs[buf][idx * 4]);
    }
  };

  stage(0, 0);
  const float* wp0 = wrow + cl;
  float4 wc0 = *(const float4*)(wp0);
  float4 wc1 = *(const float4*)(wp0 + (long)a.ldw);
  float4 wc2 = *(const float4*)(wp0 + 2 * (long)a.ldw);
  float4 wc3 = *(const float4*)(wp0 + 3 * (long)a.ldw);
  __syncthreads();

  for (int i = 0; i < nc; i++) {
    const bool hn = (i + 1) < nc;
    float4 wn0, wn1, wn2, wn3;
    if (hn) {
      const int c0n = (i + 1) << 8;
      stage((i + 1) & 1, c0n);
      const float* wp = wrow + c0n + cl;
      wn0 = *(const float4*)(wp);
      wn1 = *(const float4*)(wp + (long)a.ldw);
      wn2 = *(const float4*)(wp + 2 * (long)a.ldw);
      wn3 = *(const float4*)(wp + 3 * (long)a.ldw);
    }
    const float* xb = &xs[i & 1][0];
#pragma unroll
    for (int b = 0; b < 16; b++) {
      float4 xv = *(const float4*)(xb + (bh + b) * 256 + cl);
      acc[b * 4 + 0] += wc0.x * xv.x + wc0.y * xv.y + wc0.z * xv.z + wc0.w * xv.w;
      acc[b * 4 + 1] += wc1.x * xv.x + wc1.y * xv.y + wc1.z * xv.z + wc1.w * xv.w;
      acc[b * 4 + 2] += wc2.x * xv.x + wc2.y * xv.y + wc2.z * xv.z + wc2.w * xv.w;
      acc[b * 4 + 3] += wc3.x * xv.x + wc3.y * xv.y + wc3.z * xv.z + wc3.w * xv.w;
    }
    if (hn) { wc0 = wn0; wc1 = wn1; wc2 = wn2; wc3 = wn3; }
    __syncthreads();
  }

#pragma unroll
  for (int o = 32; o; o >>= 1) {
    bool up = (lane & o) != 0;
#pragma unroll
    for (int i = 0; i < o; i++) {
      float keep = up ? acc[i + o] : acc[i];
      float send = up ? acc[i] : acc[i + o];
      acc[i] = keep + __shfl_xor(send, o, 64);
    }
  }
  const int bo = bh + (lane >> 2);
  const int nn = n0 + (lane & 3);
  float res = acc[0];
  if (a.bias) res += a.bias[(long)g * a.biasg + nn];
  a.out[(long)g * a.outg + (long)bo * a.N + nn] = res;
}

__global__ __launch_bounds__(1024) void init_control_kernel(const float* ci, float* control) {
  control[blockIdx.x * 1024 + threadIdx.x] = ci[0];
}

// ri_w [1024, 2048] -> ri_wT [2048, 1024]
__global__ __launch_bounds__(1024) void transpose_kernel(const float* in, float* out) {
  __shared__ float t[32][33];
  int j0 = blockIdx.x * 32;
  int d0 = blockIdx.y * 32;
  int tx = threadIdx.x, ty = threadIdx.y;
  t[ty][tx] = in[(long)(d0 + ty) * 2048 + j0 + tx];
  __syncthreads();
  out[(long)(j0 + ty) * 1024 + d0 + tx] = t[tx][ty];
}

// ---------------- persistent 12-step loop ----------------

struct MacArgs {
  const float* context;
  const float* knowledge;
  const float* cq_w; const float* cq_b;
  const float* ca_w;
  const float* rm_w; const float* rm_b;
  const float* ri_wT; const float* ra_w;
  const float* wm_w; const float* wm_b;
  const float* qc_all;
  float* control; float* mem0; float* mem1;
  float* cq; float* mem_p; float* h;
  float* partial; float* readv; float* scg;
  float* outp;
};

// gemm32-style phase: 512 thr = 8 waves, wave w computes column nblk*8+w,
// all 32 batches. X tile staged in 32x512-float LDS chunks.
__device__ __forceinline__ void gemm_phase(
    float* xs, const float* X1, const float* X2, int c1, int c2,
    const float* W, int ldw, const float* bias, const float* addend,
    const float* xscale, float* out, int N, int nblk,
    int wave, int lane, int t) {
  const int C = c1 + c2;
  const int n = nblk * 8 + wave;
  const float* wrow = W + (long)n * ldw;
  float acc[32];
#pragma unroll
  for (int b = 0; b < 32; b++) acc[b] = 0.f;
  for (int c0 = 0; c0 < C; c0 += 512) {
    __syncthreads();
#pragma unroll
    for (int i = 0; i < 8; i++) {
      int idx = t + 512 * i;            // 0..4095 float4 slots
      int b = idx >> 7;                 // 128 float4 per row
      int c4 = idx & 127;
      int c = c0 + c4 * 4;
      float4 v;
      if (c < c1) v = *(const float4*)(X1 + (long)b * c1 + c);
      else        v = *(const float4*)(X2 + (long)b * c2 + (c - c1));
      if (xscale) {
        float4 s4 = *(const float4*)(xscale + c);
        v.x *= s4.x; v.y *= s4.y; v.z *= s4.z; v.w *= s4.w;
      }
      *(float4*)(xs + b * 512 + c4 * 4) = v;
    }
    __syncthreads();
#pragma unroll
    for (int i = 0; i < 2; i++) {
      int c = i * 256 + lane * 4;
      float4 wv = *(const float4*)(wrow + c0 + c);
#pragma unroll
      for (int b = 0; b < 32; b++) {
        float4 xv = *(const float4*)(xs + b * 512 + c);
        acc[b] += wv.x * xv.x + wv.y * xv.y + wv.z * xv.z + wv.w * xv.w;
      }
    }
  }
  float res = 0.f;
#pragma unroll
  for (int b = 0; b < 32; b++) {
    float v = acc[b];
#pragma unroll
    for (int off = 32; off; off >>= 1) v += __shfl_xor(v, off, 64);
    if (lane == b) res = v;
  }
  if (lane < 32) {
    float o = res;
    if (bias) o += bias[n];
    if (addend) o += addend[(long)lane * N + n];
    out[(long)lane * N + n] = o;
  }
}

__global__ __launch_bounds__(512, 2) void mac_loop_kernel(MacArgs A) {
  cg::grid_group grid = cg::this_grid();
  __shared__ float smem[16384];  // 64 KB, reused per phase
  const int p = blockIdx.x;      // 256 blocks
  const int t = threadIdx.x;     // 512 threads
  const int wave = t >> 6, lane = t & 63;

  const float* mo = A.mem0;
  float* mnbuf = A.mem1;

  for (int s = 0; s < NSTEP; s++) {
    float* mn = (s == NSTEP - 1) ? A.outp : mnbuf;

    // ---- P1: dual GEMM. p<128: cq = control@cq_w1.T + qc_all[s] + cq_b
    //                     p>=128: mem_p = mo@rm_w.T + rm_b
    if (p < 128)
      gemm_phase(smem, A.control, nullptr, 1024, 0, A.cq_w, 2048, A.cq_b,
                 A.qc_all + (long)s * 32 * 1024, nullptr, A.cq, 1024, p,
                 wave, lane, t);
    else
      gemm_phase(smem, mo, nullptr, 1024, 0, A.rm_w, 1024, A.rm_b,
                 nullptr, nullptr, A.mem_p, 1024, p - 128, wave, lane, t);
    grid.sync();

    // ---- P2: ctrl-att scores. block (b = p>>3, sg = p&7): 16 scores.
    {
      int b = p >> 3, sg = p & 7;
      float* u = smem;  // 1024
      u[t] = A.cq[b * 1024 + t] * A.ca_w[t];
      u[t + 512] = A.cq[b * 1024 + t + 512] * A.ca_w[t + 512];
      __syncthreads();
#pragma unroll
      for (int i = 0; i < 2; i++) {
        int s2 = sg * 16 + wave * 2 + i;
        const float* cr = A.context + (long)b * 128 * 1024 + (long)s2 * 1024;
        float v = 0.f;
#pragma unroll
        for (int c = 0; c < 16; c++) v += u[c * 64 + lane] * cr[c * 64 + lane];
#pragma unroll
        for (int off = 32; off; off >>= 1) v += __shfl_xor(v, off, 64);
        if (lane == 0) A.scg[b * 128 + s2] = v;
      }
    }
    grid.sync();

    // ---- P3: softmax(scores) + new_control. block (b = p>>3, dq = p&7):
    //          128 d's; 4-way s-split across thread halves.
    {
      int b = p >> 3, dq = p & 7;
      float* sw = smem;         // 128
      float* ew = smem + 128;   // 128
      float* red = smem + 256;  // 4*128
      if (t < 128) sw[t] = A.scg[b * 128 + t];
      __syncthreads();
      float m = sw[0];
      for (int s2 = 1; s2 < 128; s2++) m = fmaxf(m, sw[s2]);
      if (t < 128) ew[t] = expf(sw[t] - m);
      __syncthreads();
      float Z = 0.f;
      for (int s2 = 0; s2 < 128; s2++) Z += ew[s2];
      float invZ = 1.f / Z;
      int d = dq * 128 + (t & 127);
      int q = t >> 7;  // wave-pair uniform
      const float* ctx = A.context + (long)b * 128 * 1024;
      float acc = 0.f;
      for (int s2 = q * 32; s2 < q * 32 + 32; s2++)
        acc += ew[s2] * ctx[(long)s2 * 1024 + d];
      red[q * 128 + (t & 127)] = acc;
      __syncthreads();
      if (t < 128) {
        float v = red[t] + red[128 + t] + red[256 + t] + red[384 + t];
        A.control[b * 1024 + dq * 128 + t] = v * invZ;
      }
    }
    grid.sync();

    // ---- P4: h = (control * ra_w) @ ri_wT.T   (N=2048)
    gemm_phase(smem, A.control, nullptr, 1024, 0, A.ri_wT, 1024, nullptr,
               nullptr, A.ra_w, A.h, 2048, p, wave, lane, t);
    grid.sync();

    // ---- P5: r_att partials. 512 tasks (b,jc) -> 2 per block.
    {
      float* gl = smem;  // 64
      for (int r = 0; r < 2; r++) {
        int T = p * 2 + r, b = T >> 4, jc = T & 15, j0 = jc * 64;
        if (r) __syncthreads();
        if (t < 64)
          gl[t] = A.mem_p[b * 1024 + j0 + t] * A.h[b * 2048 + j0 + t] +
                  A.h[b * 2048 + 1024 + j0 + t];
        __syncthreads();
        const float* kb = A.knowledge + ((long)b * 1024 + j0) * 512 + t;
        float acc = 0.f;
#pragma unroll 8
        for (int jj = 0; jj < 64; jj++) acc += gl[jj] * kb[(long)jj * 512];
        A.partial[((long)jc * 32 + b) * 512 + t] = acc;
      }
    }
    grid.sync();

    // ---- P6: softmax(r_att) + read. 512 tasks (b, dg64) -> 2 per block.
    {
      float* aw = smem;          // 512
      float* red8 = smem + 512;  // 8
      for (int r = 0; r < 2; r++) {
        int T = p * 2 + r, b = T >> 4, dg = T & 15;
        if (r) __syncthreads();
        float rk = 0.f;
#pragma unroll
        for (int pp = 0; pp < 16; pp++)
          rk += A.partial[((long)pp * 32 + b) * 512 + t];
        float m = rk;
#pragma unroll
        for (int off = 32; off; off >>= 1) m = fmaxf(m, __shfl_xor(m, off, 64));
        if (lane == 0) red8[wave] = m;
        __syncthreads();
        m = red8[0];
        for (int q = 1; q < 8; q++) m = fmaxf(m, red8[q]);
        __syncthreads();  // all reads done before red8 rewrite
        float e = expf(rk - m);
        float zz = e;
#pragma unroll
        for (int off = 32; off; off >>= 1) zz += __shfl_xor(zz, off, 64);
        if (lane == 0) red8[wave] = zz;
        __syncthreads();
        float Z = 0.f;
        for (int q = 0; q < 8; q++) Z += red8[q];
        aw[t] = e / Z;
        __syncthreads();
        int d0 = dg * 64 + wave * 8;
        float acc8[8];
#pragma unroll
        for (int dd = 0; dd < 8; dd++) acc8[dd] = 0.f;
        const float* kb = A.knowledge + ((long)b * 1024 + d0) * 512;
#pragma unroll
        for (int kc = 0; kc < 8; kc++) {
          int kk = kc * 64 + lane;
          float av = aw[kk];
#pragma unroll
          for (int dd = 0; dd < 8; dd++) acc8[dd] += av * kb[(long)dd * 512 + kk];
        }
#pragma unroll
        for (int dd = 0; dd < 8; dd++) {
          float v = acc8[dd];
#pragma unroll
          for (int off = 32; off; off >>= 1) v += __shfl_xor(v, off, 64);
          if (lane == dd) A.readv[b * 1024 + d0 + dd] = v;
        }
      }
    }
    grid.sync();

    // ---- P7: new_memory = readv@wm_w1.T + mo@wm_w2.T + wm_b  (C=2048)
    if (p < 128)
      gemm_phase(smem, A.readv, mo, 1024, 1024, A.wm_w, 2048, A.wm_b,
                 nullptr, nullptr, mn, 1024, p, wave, lane, t);
    grid.sync();

    if (s < NSTEP - 1) {
      const float* tmp = mo; mo = mnbuf; mnbuf = (float*)tmp;
    }
  }
}

static inline void launch_gemm_wide(const float* X1, long x1g, int c1,
                                    const float* W, int ldw, long wg,
                                    const float* bias, long biasg,
                                    float* out, long outg, int N, int G,
                                    hipStream_t stream) {
  GemmArgs a{X1, x1g, nullptr, 0, c1, 0, W, ldw, wg, bias, biasg,
             nullptr, 0, nullptr, out, outg, N};
  gemm_wide_kernel<<<dim3(N / 8, G), 256, 0, stream>>>(a);
}

extern "C" void kernel_launch(void* const* d_in, const int* in_sizes, int n_in,
                              void* d_out, int out_size, void* d_ws, size_t ws_size,
                              hipStream_t stream) {
  const float* context      = (const float*)d_in[0];
  const float* question     = (const float*)d_in[1];
  const float* knowledge    = (const float*)d_in[2];
  const float* control_init = (const float*)d_in[3];
  const float* pa_w = (const float*)d_in[4];
  const float* pa_b = (const float*)d_in[5];
  const float* cq_w = (const float*)d_in[6];
  const float* cq_b = (const float*)d_in[7];
  const float* ca_w = (const float*)d_in[8];
  // d_in[9] ca_b: softmax-invariant, dropped
  const float* rm_w = (const float*)d_in[10];
  const float* rm_b = (const float*)d_in[11];
  const float* ri_w = (const float*)d_in[12];
  // d_in[13] ri_b: softmax-invariant, dropped
  const float* ra_w = (const float*)d_in[14];
  // d_in[15] ra_b: softmax-invariant, dropped
  const float* wm_w = (const float*)d_in[16];
  const float* wm_b = (const float*)d_in[17];
  float* out = (float*)d_out;

  float* p = (float*)d_ws;
  float* q_pa_all = p; p += NSTEP * 32 * 1024;
  float* qc_all   = p; p += NSTEP * 32 * 1024;
  float* ri_wT    = p; p += 2048 * 1024;
  float* control  = p; p += 32 * 1024;
  float* mem0     = p; p += 32 * 1024;
  float* mem1     = p; p += 32 * 1024;
  float* cq       = p; p += 32 * 1024;
  float* mem_p    = p; p += 32 * 1024;
  float* h        = p; p += 32 * 2048;
  float* partial  = p; p += 16 * 32 * 512;
  float* readv    = p; p += 32 * 1024;
  float* scg      = p; p += 32 * 128;

  init_control_kernel<<<32, 1024, 0, stream>>>(control_init, control);
  transpose_kernel<<<dim3(64, 32), dim3(32, 32), 0, stream>>>(ri_w, ri_wT);
  // q_pa_all[s] = question @ pa_w[s].T + pa_b[s]   (96 MB W stream)
  launch_gemm_wide(question, 0, 2048, pa_w, 2048, 1024L * 2048,
                   pa_b, 1024, q_pa_all, 32 * 1024, 1024, NSTEP, stream);
  hipMemcpyAsync(mem0, q_pa_all, 32 * 1024 * sizeof(float), hipMemcpyDeviceToDevice, stream);
  // qc_all[s] = q_pa_all[s] @ cq_w[:, D:].T   (hoisted out of the loop)
  launch_gemm_wide(q_pa_all, 32 * 1024, 1024, cq_w + 1024, 2048, 0,
                   nullptr, 0, qc_all, 32 * 1024, 1024, NSTEP, stream);

  // persistent cooperative 12-step loop
  MacArgs A{context, knowledge, cq_w, cq_b, ca_w, rm_w, rm_b, ri_wT, ra_w,
            wm_w, wm_b, qc_all, control, mem0, mem1, cq, mem_p, h,
            partial, readv, scg, out};
  void* kargs[] = {(void*)&A};
  hipLaunchCooperativeKernel((const void*)mac_loop_kernel, dim3(256), dim3(512),
                             kargs, 0, stream);
}

// Round 6
// 1409.930 us; speedup vs baseline: 3.4925x; 3.4925x over previous
//
#include <hip/hip_runtime.h>

// MAC network forward, restructured:
//  - inter2 GEMM (34 GMAC/step) algebraically collapsed via linearity of the
//    r_att contraction: r_att[b,k] = sum_j knowledge[b,j,k]*g[b,j],
//    g = mem_p * h[:, :D] + h[:, D:],  h = (new_control*ra_w) @ ri_w.
//  - q_pa part of control-unit GEMM hoisted out of the step loop (qc_all).
//  - ca_b / ra_b / ri_b are per-row constants under softmax -> dropped.
// All fp32.
//
// R6: back to multi-dispatch (R5 grid.sync cost ~38us + L2 flush per sync ->
// FETCH 2GB/dispatch; persistent kernel abandoned). Dispatch-count reduction
// via INDEPENDENT-work fusion instead (R4 evidence: each removed small
// dispatch boundary ~15-30us):
//  - ctrl_g2_kernel: P2(s) || G2(s) hetero fusion (mem_p depends only on
//    memory, not cq). Also hides P2's 32-block narrowness.
//  - gemm32_dual:    G3(s) || G1(s+1) (G1(s+1) needs only control(s)).
// Per-step dispatches 7 -> 5. gemm_wide = exact R3 config (66us proven).

#define NSTEP 12

struct GemmArgs {
  const float* X1; long x1g;   // [32, c1], per-group stride
  const float* X2; long x2g;   // [32, c2] or null (concat second half)
  int c1, c2;
  const float* W; int ldw; long wg;      // W[N, C] row-major (out = X @ W.T)
  const float* bias; long biasg;         // len N or null
  const float* addend; long addg;        // [32, N] or null
  const float* xscale;                   // len C or null (elementwise on X)
  float* out; long outg;                 // [32, N]
  int N;
};

// out[b,n] = sum_c X[b,c]*W[n,c] (+bias +addend). 256 thr = 4 waves,
// one output column per wave, X tile (32 x 512) in LDS.
__device__ __forceinline__ void gemm32_body(const GemmArgs& a, int bx) {
  __shared__ float xs[32 * 512];  // 64 KB
  const int g = blockIdx.y;
  const int C = a.c1 + a.c2;
  const float* X1 = a.X1 + (long)g * a.x1g;
  const float* X2 = a.X2 ? a.X2 + (long)g * a.x2g : nullptr;
  const float* W = a.W + (long)g * a.wg;
  const int wave = threadIdx.x >> 6;
  const int lane = threadIdx.x & 63;
  const int n = bx * 4 + wave;
  const float* wrow = W + (long)n * a.ldw;
  float acc[32];
#pragma unroll
  for (int b = 0; b < 32; b++) acc[b] = 0.f;

  for (int c0 = 0; c0 < C; c0 += 512) {
    __syncthreads();  // protect previous chunk's reads
#pragma unroll
    for (int i = 0; i < 16; i++) {
      int idx = threadIdx.x + 256 * i;  // 0..4095 float4 slots
      int b = idx >> 7;                 // 128 float4 per row
      int c4 = idx & 127;
      int c = c0 + c4 * 4;              // global column
      float4 v;
      if (c < a.c1) v = *(const float4*)(X1 + (long)b * a.c1 + c);
      else          v = *(const float4*)(X2 + (long)b * a.c2 + (c - a.c1));
      if (a.xscale) {
        float4 s = *(const float4*)(a.xscale + c);
        v.x *= s.x; v.y *= s.y; v.z *= s.z; v.w *= s.w;
      }
      *(float4*)(xs + b * 512 + c4 * 4) = v;
    }
    __syncthreads();
#pragma unroll
    for (int i = 0; i < 2; i++) {
      int c = i * 256 + lane * 4;
      float4 wv = *(const float4*)(wrow + c0 + c);
#pragma unroll
      for (int b = 0; b < 32; b++) {
        float4 xv = *(const float4*)(xs + b * 512 + c);
        acc[b] += wv.x * xv.x + wv.y * xv.y + wv.z * xv.z + wv.w * xv.w;
      }
    }
  }
  float res = 0.f;
#pragma unroll
  for (int b = 0; b < 32; b++) {
    float v = acc[b];
#pragma unroll
    for (int off = 32; off; off >>= 1) v += __shfl_xor(v, off, 64);
    if (lane == b) res = v;
  }
  if (lane < 32) {
    float o = res;
    if (a.bias) o += a.bias[(long)g * a.biasg + n];
    if (a.addend) o += a.addend[(long)g * a.addg + (long)lane * a.N + n];
    a.out[(long)g * a.outg + (long)lane * a.N + n] = o;
  }
}

__global__ __launch_bounds__(256) void gemm32_kernel(GemmArgs a) {
  gemm32_body(a, blockIdx.x);
}

// Two independent gemm32 problems in one dispatch, packed along grid.x.
__global__ __launch_bounds__(256) void gemm32_dual_kernel(GemmArgs a0, GemmArgs a1, int split) {
  int bx = blockIdx.x;
  if (bx < split) gemm32_body(a0, bx);
  else            gemm32_body(a1, bx - split);
}

__device__ __forceinline__ void gload_lds16(const float* g, float* l) {
  __builtin_amdgcn_global_load_lds(
      (const __attribute__((address_space(1))) void*)g,
      (__attribute__((address_space(3))) void*)l, 16, 0, 0);
}

// Streaming thin-M GEMM for large W (pa, qc). X1-only. R3-proven config:
// 256 thr = 4 waves, 8-col x 32-row tile, global_load_lds double-buffered
// 32KB chunks, W regs prefetched one chunk ahead. VGPR 112, no spill.
__global__ __launch_bounds__(256, 2) void gemm_wide_kernel(GemmArgs a) {
  __shared__ float xs[2][32 * 256];  // 2 x 32 KB
  const int g = blockIdx.y;
  const int C = a.c1;
  const int nc = C >> 8;
  const float* X1 = a.X1 + (long)g * a.x1g;
  const float* W = a.W + (long)g * a.wg;
  const int wave = threadIdx.x >> 6;
  const int lane = threadIdx.x & 63;
  const int n0 = blockIdx.x * 8 + (wave >> 1) * 4;
  const int bh = (wave & 1) * 16;
  const float* wrow = W + (long)n0 * a.ldw;
  const int cl = lane * 4;

  float acc[64];
#pragma unroll
  for (int v = 0; v < 64; v++) acc[v] = 0.f;

  auto stage = [&](int buf, int c0) {
#pragma unroll
    for (int r = 0; r < 8; r++) {
      int idx = threadIdx.x + 256 * r;
      int b = idx >> 6;
      gload_lds16(X1 + (long)b * C + c0 + (idx & 63) * 4, &xs[buf][idx * 4]);
    }
  };

  stage(0, 0);
  const float* wp0 = wrow + cl;
  float4 wc0 = *(const float4*)(wp0);
  float4 wc1 = *(const float4*)(wp0 + (long)a.ldw);
  float4 wc2 = *(const float4*)(wp0 + 2 * (long)a.ldw);
  float4 wc3 = *(const float4*)(wp0 + 3 * (long)a.ldw);
  __syncthreads();

  for (int i = 0; i < nc; i++) {
    const bool hn = (i + 1) < nc;
    float4 wn0, wn1, wn2, wn3;
    if (hn) {
      const int c0n = (i + 1) << 8;
      stage((i + 1) & 1, c0n);
      const float* wp = wrow + c0n + cl;
      wn0 = *(const float4*)(wp);
      wn1 = *(const float4*)(wp + (long)a.ldw);
      wn2 = *(const float4*)(wp + 2 * (long)a.ldw);
      wn3 = *(const float4*)(wp + 3 * (long)a.ldw);
    }
    const float* xb = &xs[i & 1][0];
#pragma unroll
    for (int b = 0; b < 16; b++) {
      float4 xv = *(const float4*)(xb + (bh + b) * 256 + cl);
      acc[b * 4 + 0] += wc0.x * xv.x + wc0.y * xv.y + wc0.z * xv.z + wc0.w * xv.w;
      acc[b * 4 + 1] += wc1.x * xv.x + wc1.y * xv.y + wc1.z * xv.z + wc1.w * xv.w;
      acc[b * 4 + 2] += wc2.x * xv.x + wc2.y * xv.y + wc2.z * xv.z + wc2.w * xv.w;
      acc[b * 4 + 3] += wc3.x * xv.x + wc3.y * xv.y + wc3.z * xv.z + wc3.w * xv.w;
    }
    if (hn) { wc0 = wn0; wc1 = wn1; wc2 = wn2; wc3 = wn3; }
    __syncthreads();
  }

#pragma unroll
  for (int o = 32; o; o >>= 1) {
    bool up = (lane & o) != 0;
#pragma unroll
    for (int i = 0; i < o; i++) {
      float keep = up ? acc[i + o] : acc[i];
      float send = up ? acc[i] : acc[i + o];
      acc[i] = keep + __shfl_xor(send, o, 64);
    }
  }
  const int bo = bh + (lane >> 2);
  const int nn = n0 + (lane & 3);
  float res = acc[0];
  if (a.bias) res += a.bias[(long)g * a.biasg + nn];
  a.out[(long)g * a.outg + (long)bo * a.N + nn] = res;
}

__global__ __launch_bounds__(1024) void init_control_kernel(const float* ci, float* control) {
  control[blockIdx.x * 1024 + threadIdx.x] = ci[0];
}

// ri_w [1024, 2048] -> ri_wT [2048, 1024]
__global__ __launch_bounds__(1024) void transpose_kernel(const float* in, float* out) {
  __shared__ float t[32][33];
  int j0 = blockIdx.x * 32;
  int d0 = blockIdx.y * 32;
  int tx = threadIdx.x, ty = threadIdx.y;
  t[ty][tx] = in[(long)(d0 + ty) * 2048 + j0 + tx];
  __syncthreads();
  out[(long)(j0 + ty) * 1024 + d0 + tx] = t[tx][ty];
}

// Hetero fusion: blocks [0,64): G2 gemm (mem_p = mo @ rm_w.T + rm_b),
// 16 cols per block (16 waves x 1 col); blocks [64,96): ctrl-att (P2),
// one block per batch row. 1024 threads, 64 KB LDS both roles.
__global__ __launch_bounds__(1024) void ctrl_g2_kernel(GemmArgs g2,
                                                       const float* cq,
                                                       const float* context,
                                                       const float* ca_w,
                                                       float* control) {
  __shared__ float smem[32 * 512];  // 64 KB
  const int bx = blockIdx.x;
  const int t = threadIdx.x;
  const int wave = t >> 6, lane = t & 63;

  if (bx < 64) {
    // ---- G2 role: gemm32 pattern at 1024 thr / 16 cols ----
    const float* X1 = g2.X1;
    const int C = g2.c1;
    const int n = bx * 16 + wave;
    const float* wrow = g2.W + (long)n * g2.ldw;
    float acc[32];
#pragma unroll
    for (int b = 0; b < 32; b++) acc[b] = 0.f;
    for (int c0 = 0; c0 < C; c0 += 512) {
      __syncthreads();
#pragma unroll
      for (int i = 0; i < 4; i++) {
        int idx = t + 1024 * i;  // 0..4095 float4 slots
        int b = idx >> 7, c4 = idx & 127;
        *(float4*)(smem + b * 512 + c4 * 4) =
            *(const float4*)(X1 + (long)b * C + c0 + c4 * 4);
      }
      __syncthreads();
#pragma unroll
      for (int i = 0; i < 2; i++) {
        int c = i * 256 + lane * 4;
        float4 wv = *(const float4*)(wrow + c0 + c);
#pragma unroll
        for (int b = 0; b < 32; b++) {
          float4 xv = *(const float4*)(smem + b * 512 + c);
          acc[b] += wv.x * xv.x + wv.y * xv.y + wv.z * xv.z + wv.w * xv.w;
        }
      }
    }
    float res = 0.f;
#pragma unroll
    for (int b = 0; b < 32; b++) {
      float v = acc[b];
#pragma unroll
      for (int off = 32; off; off >>= 1) v += __shfl_xor(v, off, 64);
      if (lane == b) res = v;
    }
    if (lane < 32) {
      float o = res;
      if (g2.bias) o += g2.bias[n];
      g2.out[(long)lane * g2.N + n] = o;
    }
  } else {
    // ---- P2 role: ctrl-att (scores, softmax, contract) for b = bx-64 ----
    const int b = bx - 64;
    float* u = smem;         // 1024
    float* sc = smem + 1024; // 128
    u[t] = cq[b * 1024 + t] * ca_w[t];
    __syncthreads();
    const float* ctx = context + (long)b * 128 * 1024;
#pragma unroll
    for (int i = 0; i < 8; i++) {
      int s2 = wave * 8 + i;  // 16 waves x 8 = 128 scores
      float v = 0.f;
#pragma unroll
      for (int c = 0; c < 16; c++) v += u[c * 64 + lane] * ctx[(long)s2 * 1024 + c * 64 + lane];
#pragma unroll
      for (int off = 32; off; off >>= 1) v += __shfl_xor(v, off, 64);
      if (lane == 0) sc[s2] = v;  // ca_b dropped (softmax-invariant)
    }
    __syncthreads();
    if (wave == 0) {
      float a0 = sc[lane], a1 = sc[lane + 64];
      float m = fmaxf(a0, a1);
#pragma unroll
      for (int off = 32; off; off >>= 1) m = fmaxf(m, __shfl_xor(m, off, 64));
      float e0 = expf(a0 - m), e1 = expf(a1 - m);
      float s2 = e0 + e1;
#pragma unroll
      for (int off = 32; off; off >>= 1) s2 += __shfl_xor(s2, off, 64);
      float inv = 1.f / s2;
      sc[lane] = e0 * inv;
      sc[lane + 64] = e1 * inv;
    }
    __syncthreads();
    float acc = 0.f;
    for (int s2 = 0; s2 < 128; s2++) acc += sc[s2] * ctx[(long)s2 * 1024 + t];
    control[b * 1024 + t] = acc;
  }
}

// r_att partials: partial[jc][b][k] = sum_{j in chunk jc} g[b,j]*knowledge[b,j,k]
__global__ __launch_bounds__(512) void ratt_kernel(const float* knowledge, const float* mem_p,
                                                   const float* h, float* partial) {
  int b = blockIdx.x, jc = blockIdx.y;
  int j0 = jc * 64;
  __shared__ float gl[64];
  if (threadIdx.x < 64) {
    int j = j0 + threadIdx.x;
    gl[threadIdx.x] = mem_p[b * 1024 + j] * h[b * 2048 + j] + h[b * 2048 + 1024 + j];
  }
  __syncthreads();
  int k = threadIdx.x;  // 512 threads <-> K=512
  const float* kb = knowledge + ((long)b * 1024 + j0) * 512 + k;
  float acc = 0.f;
#pragma unroll 8
  for (int jj = 0; jj < 64; jj++) acc += gl[jj] * kb[(long)jj * 512];
  partial[((long)jc * 32 + b) * 512 + k] = acc;
}

// softmax(r_att) + read[b,d] = sum_k a[k]*knowledge[b,d,k]
__global__ __launch_bounds__(256) void read_kernel(const float* partial, const float* knowledge,
                                                   float* readv) {
  int b = blockIdx.x, dg = blockIdx.y;
  __shared__ float aw[512];
  __shared__ float red[4];
  int tid = threadIdx.x;
  int wave = tid >> 6, lane = tid & 63;
  int k0 = tid * 2;
  float r0 = 0.f, r1 = 0.f;
#pragma unroll
  for (int p = 0; p < 16; p++) {
    const float* pp = partial + ((long)p * 32 + b) * 512;
    r0 += pp[k0];
    r1 += pp[k0 + 1];
  }
  float m = fmaxf(r0, r1);
#pragma unroll
  for (int off = 32; off; off >>= 1) m = fmaxf(m, __shfl_xor(m, off, 64));
  if (lane == 0) red[wave] = m;
  __syncthreads();
  m = fmaxf(fmaxf(red[0], red[1]), fmaxf(red[2], red[3]));
  __syncthreads();  // all reads of red done before rewrite
  float e0 = expf(r0 - m), e1 = expf(r1 - m);
  float s2 = e0 + e1;
#pragma unroll
  for (int off = 32; off; off >>= 1) s2 += __shfl_xor(s2, off, 64);
  if (lane == 0) red[wave] = s2;
  __syncthreads();
  s2 = red[0] + red[1] + red[2] + red[3];
  float inv = 1.f / s2;
  aw[k0] = e0 * inv;
  aw[k0 + 1] = e1 * inv;
  __syncthreads();
  int d0 = dg * 32 + wave * 8;  // 4 waves x 8 d each
  float acc[8];
#pragma unroll
  for (int i = 0; i < 8; i++) acc[i] = 0.f;
  const float* kb = knowledge + ((long)b * 1024 + d0) * 512;
  for (int kc = 0; kc < 8; kc++) {
    int kk = kc * 64 + lane;
    float av = aw[kk];
#pragma unroll
    for (int dd = 0; dd < 8; dd++) acc[dd] += av * kb[(long)dd * 512 + kk];
  }
#pragma unroll
  for (int dd = 0; dd < 8; dd++) {
    float v = acc[dd];
#pragma unroll
    for (int off = 32; off; off >>= 1) v += __shfl_xor(v, off, 64);
    if (lane == dd) readv[b * 1024 + d0 + dd] = v;
  }
}

static inline void launch_gemm_wide(const float* X1, long x1g, int c1,
                                    const float* W, int ldw, long wg,
                                    const float* bias, long biasg,
                                    float* out, long outg, int N, int G,
                                    hipStream_t stream) {
  GemmArgs a{X1, x1g, nullptr, 0, c1, 0, W, ldw, wg, bias, biasg,
             nullptr, 0, nullptr, out, outg, N};
  gemm_wide_kernel<<<dim3(N / 8, G), 256, 0, stream>>>(a);
}

extern "C" void kernel_launch(void* const* d_in, const int* in_sizes, int n_in,
                              void* d_out, int out_size, void* d_ws, size_t ws_size,
                              hipStream_t stream) {
  const float* context      = (const float*)d_in[0];
  const float* question     = (const float*)d_in[1];
  const float* knowledge    = (const float*)d_in[2];
  const float* control_init = (const float*)d_in[3];
  const float* pa_w = (const float*)d_in[4];
  const float* pa_b = (const float*)d_in[5];
  const float* cq_w = (const float*)d_in[6];
  const float* cq_b = (const float*)d_in[7];
  const float* ca_w = (const float*)d_in[8];
  // d_in[9] ca_b: softmax-invariant, dropped
  const float* rm_w = (const float*)d_in[10];
  const float* rm_b = (const float*)d_in[11];
  const float* ri_w = (const float*)d_in[12];
  // d_in[13] ri_b: softmax-invariant, dropped
  const float* ra_w = (const float*)d_in[14];
  // d_in[15] ra_b: softmax-invariant, dropped
  const float* wm_w = (const float*)d_in[16];
  const float* wm_b = (const float*)d_in[17];
  float* out = (float*)d_out;

  float* p = (float*)d_ws;
  float* q_pa_all = p; p += NSTEP * 32 * 1024;
  float* qc_all   = p; p += NSTEP * 32 * 1024;
  float* ri_wT    = p; p += 2048 * 1024;
  float* control  = p; p += 32 * 1024;
  float* mem0     = p; p += 32 * 1024;
  float* mem1     = p; p += 32 * 1024;
  float* cq       = p; p += 32 * 1024;
  float* mem_p    = p; p += 32 * 1024;
  float* h        = p; p += 32 * 2048;
  float* partial  = p; p += 16 * 32 * 512;
  float* readv    = p; p += 32 * 1024;

  init_control_kernel<<<32, 1024, 0, stream>>>(control_init, control);
  transpose_kernel<<<dim3(64, 32), dim3(32, 32), 0, stream>>>(ri_w, ri_wT);
  // q_pa_all[s] = question @ pa_w[s].T + pa_b[s]   (96 MB W stream)
  launch_gemm_wide(question, 0, 2048, pa_w, 2048, 1024L * 2048,
                   pa_b, 1024, q_pa_all, 32 * 1024, 1024, NSTEP, stream);
  hipMemcpyAsync(mem0, q_pa_all, 32 * 1024 * sizeof(float), hipMemcpyDeviceToDevice, stream);
  // qc_all[s] = q_pa_all[s] @ cq_w[:, D:].T   (hoisted out of the loop)
  launch_gemm_wide(q_pa_all, 32 * 1024, 1024, cq_w + 1024, 2048, 0,
                   nullptr, 0, qc_all, 32 * 1024, 1024, NSTEP, stream);

  // G1(0): cq = control @ cq_w[:, :D].T + qc_all[0] + cq_b
  {
    GemmArgs g1{control, 0, nullptr, 0, 1024, 0, cq_w, 2048, 0,
                cq_b, 0, qc_all, 0, nullptr, cq, 0, 1024};
    gemm32_kernel<<<256, 256, 0, stream>>>(g1);
  }

  float* mems[2] = {mem0, mem1};
  for (int s = 0; s < NSTEP; s++) {
    float* mo = mems[s & 1];
    float* mn = (s == NSTEP - 1) ? out : mems[(s + 1) & 1];

    // D_alpha: P2(s) [ctrl-att from cq -> control] || G2(s) [mem_p = mo@rm_w.T + rm_b]
    {
      GemmArgs g2{mo, 0, nullptr, 0, 1024, 0, rm_w, 1024, 0,
                  rm_b, 0, nullptr, 0, nullptr, mem_p, 0, 1024};
      ctrl_g2_kernel<<<96, 1024, 0, stream>>>(g2, cq, context, ca_w, control);
    }

    // D_beta: G3(s) [h = (control*ra_w) @ ri_wT.T] || G1(s+1) [next cq]
    {
      GemmArgs g3{control, 0, nullptr, 0, 1024, 0, ri_wT, 1024, 0,
                  nullptr, 0, nullptr, 0, ra_w, h, 0, 2048};
      if (s < NSTEP - 1) {
        GemmArgs g1{control, 0, nullptr, 0, 1024, 0, cq_w, 2048, 0,
                    cq_b, 0, qc_all + (long)(s + 1) * 32 * 1024, 0, nullptr,
                    cq, 0, 1024};
        gemm32_dual_kernel<<<768, 256, 0, stream>>>(g3, g1, 512);
      } else {
        gemm32_kernel<<<512, 256, 0, stream>>>(g3);
      }
    }

    // D_gamma: r_att partials
    ratt_kernel<<<dim3(32, 16), 512, 0, stream>>>(knowledge, mem_p, h, partial);
    // D_delta: softmax + read
    read_kernel<<<dim3(32, 32), 256, 0, stream>>>(partial, knowledge, readv);
    // D_eps: new_memory = read@wm_w[:, :D].T + memory@wm_w[:, D:].T + wm_b
    {
      GemmArgs g6{readv, 0, mo, 0, 1024, 1024, wm_w, 2048, 0,
                  wm_b, 0, nullptr, 0, nullptr, mn, 0, 1024};
      gemm32_kernel<<<256, 256, 0, stream>>>(g6);
    }
  }
}

// Round 7
// 1386.733 us; speedup vs baseline: 3.5510x; 1.0167x over previous
//
#include <hip/hip_runtime.h>

// MAC network forward, restructured:
//  - inter2 GEMM (34 GMAC/step) algebraically collapsed via linearity of the
//    r_att contraction: r_att[b,k] = sum_j knowledge[b,j,k]*g[b,j],
//    g = mem_p * h[:, :D] + h[:, D:],  h = (new_control*ra_w) @ ri_w.
//  - q_pa part of control-unit GEMM hoisted out of the step loop (qc_all).
//  - ca_b / ra_b / ri_b are per-row constants under softmax -> dropped.
// All fp32.
//
// R7 (on R6 skeleton, best=1410us):
//  - gemm_wide: 16 cols/block via 512 thr + launch_bounds(512,2). R6's
//    66us was LLC-BW bound on X re-staging (384MB X vs 96MB W). R4's
//    identical structure failed ONLY on the VGPR cap (empirical model:
//    cap ~ 256/minWaves; (512,4)->64 spilled; (512,2)->256 budget, kernel
//    needs ~112). X traffic halves; occupancy 2->4 waves/SIMD.
//  - G6 split: memp2 = mo@wm_w[:,D:].T + wm_b depends only on mem(s) ->
//    computed in D_alpha (3-role kernel); G6 runs C=1024 with memp2 addend.
//  - read_kernel: 128 d/block (grid 1024->256): 4x less partial re-read
//    and softmax recompute.

#define NSTEP 12

struct GemmArgs {
  const float* X1; long x1g;   // [32, c1], per-group stride
  const float* X2; long x2g;   // [32, c2] or null (concat second half)
  int c1, c2;
  const float* W; int ldw; long wg;      // W[N, C] row-major (out = X @ W.T)
  const float* bias; long biasg;         // len N or null
  const float* addend; long addg;        // [32, N] or null
  const float* xscale;                   // len C or null (elementwise on X)
  float* out; long outg;                 // [32, N]
  int N;
};

// out[b,n] = sum_c X[b,c]*W[n,c] (+bias +addend). 256 thr = 4 waves,
// one output column per wave, X tile (32 x 512) in LDS.
__device__ __forceinline__ void gemm32_body(const GemmArgs& a, int bx) {
  __shared__ float xs[32 * 512];  // 64 KB
  const int g = blockIdx.y;
  const int C = a.c1 + a.c2;
  const float* X1 = a.X1 + (long)g * a.x1g;
  const float* X2 = a.X2 ? a.X2 + (long)g * a.x2g : nullptr;
  const float* W = a.W + (long)g * a.wg;
  const int wave = threadIdx.x >> 6;
  const int lane = threadIdx.x & 63;
  const int n = bx * 4 + wave;
  const float* wrow = W + (long)n * a.ldw;
  float acc[32];
#pragma unroll
  for (int b = 0; b < 32; b++) acc[b] = 0.f;

  for (int c0 = 0; c0 < C; c0 += 512) {
    __syncthreads();  // protect previous chunk's reads
#pragma unroll
    for (int i = 0; i < 16; i++) {
      int idx = threadIdx.x + 256 * i;  // 0..4095 float4 slots
      int b = idx >> 7;                 // 128 float4 per row
      int c4 = idx & 127;
      int c = c0 + c4 * 4;              // global column
      float4 v;
      if (c < a.c1) v = *(const float4*)(X1 + (long)b * a.c1 + c);
      else          v = *(const float4*)(X2 + (long)b * a.c2 + (c - a.c1));
      if (a.xscale) {
        float4 s = *(const float4*)(a.xscale + c);
        v.x *= s.x; v.y *= s.y; v.z *= s.z; v.w *= s.w;
      }
      *(float4*)(xs + b * 512 + c4 * 4) = v;
    }
    __syncthreads();
#pragma unroll
    for (int i = 0; i < 2; i++) {
      int c = i * 256 + lane * 4;
      float4 wv = *(const float4*)(wrow + c0 + c);
#pragma unroll
      for (int b = 0; b < 32; b++) {
        float4 xv = *(const float4*)(xs + b * 512 + c);
        acc[b] += wv.x * xv.x + wv.y * xv.y + wv.z * xv.z + wv.w * xv.w;
      }
    }
  }
  float res = 0.f;
#pragma unroll
  for (int b = 0; b < 32; b++) {
    float v = acc[b];
#pragma unroll
    for (int off = 32; off; off >>= 1) v += __shfl_xor(v, off, 64);
    if (lane == b) res = v;
  }
  if (lane < 32) {
    float o = res;
    if (a.bias) o += a.bias[(long)g * a.biasg + n];
    if (a.addend) o += a.addend[(long)g * a.addg + (long)lane * a.N + n];
    a.out[(long)g * a.outg + (long)lane * a.N + n] = o;
  }
}

__global__ __launch_bounds__(256) void gemm32_kernel(GemmArgs a) {
  gemm32_body(a, blockIdx.x);
}

// Two independent gemm32 problems in one dispatch, packed along grid.x.
__global__ __launch_bounds__(256) void gemm32_dual_kernel(GemmArgs a0, GemmArgs a1, int split) {
  int bx = blockIdx.x;
  if (bx < split) gemm32_body(a0, bx);
  else            gemm32_body(a1, bx - split);
}

__device__ __forceinline__ void gload_lds16(const float* g, float* l) {
  __builtin_amdgcn_global_load_lds(
      (const __attribute__((address_space(1))) void*)g,
      (__attribute__((address_space(3))) void*)l, 16, 0, 0);
}

// Streaming thin-M GEMM for large W (pa, qc). X1-only.
// 512 thr = 8 waves, 16-col x 32-row tile. Wave w: cols n0+(w>>1)*4..+3,
// batch half (w&1)*16..+15. X staged via global_load_lds, double-buffered
// 32KB chunks; W regs prefetched one chunk ahead. acc[64]/wave, ~112 VGPR;
// launch_bounds(512,2) -> 256-reg budget (no spill), LDS limits 2 blk/CU
// = 4 waves/SIMD.
__global__ __launch_bounds__(512, 2) void gemm_wide_kernel(GemmArgs a) {
  __shared__ float xs[2][32 * 256];  // 2 x 32 KB
  const int g = blockIdx.y;
  const int C = a.c1;
  const int nc = C >> 8;
  const float* X1 = a.X1 + (long)g * a.x1g;
  const float* W = a.W + (long)g * a.wg;
  const int wave = threadIdx.x >> 6;
  const int lane = threadIdx.x & 63;
  const int n0 = blockIdx.x * 16 + (wave >> 1) * 4;
  const int bh = (wave & 1) * 16;
  const float* wrow = W + (long)n0 * a.ldw;
  const int cl = lane * 4;

  float acc[64];
#pragma unroll
  for (int v = 0; v < 64; v++) acc[v] = 0.f;

  // stage one 32x256 chunk; thread t, call r: slot idx = t + 512r,
  // row b = idx>>6 is wave-uniform; LDS dest linear base + lane*16.
  auto stage = [&](int buf, int c0) {
#pragma unroll
    for (int r = 0; r < 4; r++) {
      int idx = threadIdx.x + 512 * r;
      int b = idx >> 6;
      gload_lds16(X1 + (long)b * C + c0 + (idx & 63) * 4, &xs[buf][idx * 4]);
    }
  };

  stage(0, 0);
  const float* wp0 = wrow + cl;
  float4 wc0 = *(const float4*)(wp0);
  float4 wc1 = *(const float4*)(wp0 + (long)a.ldw);
  float4 wc2 = *(const float4*)(wp0 + 2 * (long)a.ldw);
  float4 wc3 = *(const float4*)(wp0 + 3 * (long)a.ldw);
  __syncthreads();

  for (int i = 0; i < nc; i++) {
    const bool hn = (i + 1) < nc;
    float4 wn0, wn1, wn2, wn3;
    if (hn) {
      const int c0n = (i + 1) << 8;
      stage((i + 1) & 1, c0n);
      const float* wp = wrow + c0n + cl;
      wn0 = *(const float4*)(wp);
      wn1 = *(const float4*)(wp + (long)a.ldw);
      wn2 = *(const float4*)(wp + 2 * (long)a.ldw);
      wn3 = *(const float4*)(wp + 3 * (long)a.ldw);
    }
    const float* xb = &xs[i & 1][0];
#pragma unroll
    for (int b = 0; b < 16; b++) {
      float4 xv = *(const float4*)(xb + (bh + b) * 256 + cl);
      acc[b * 4 + 0] += wc0.x * xv.x + wc0.y * xv.y + wc0.z * xv.z + wc0.w * xv.w;
      acc[b * 4 + 1] += wc1.x * xv.x + wc1.y * xv.y + wc1.z * xv.z + wc1.w * xv.w;
      acc[b * 4 + 2] += wc2.x * xv.x + wc2.y * xv.y + wc2.z * xv.z + wc2.w * xv.w;
      acc[b * 4 + 3] += wc3.x * xv.x + wc3.y * xv.y + wc3.z * xv.z + wc3.w * xv.w;
    }
    if (hn) { wc0 = wn0; wc1 = wn1; wc2 = wn2; wc3 = wn3; }
    __syncthreads();
  }

#pragma unroll
  for (int o = 32; o; o >>= 1) {
    bool up = (lane & o) != 0;
#pragma unroll
    for (int i = 0; i < o; i++) {
      float keep = up ? acc[i + o] : acc[i];
      float send = up ? acc[i] : acc[i + o];
      acc[i] = keep + __shfl_xor(send, o, 64);
    }
  }
  const int bo = bh + (lane >> 2);
  const int nn = n0 + (lane & 3);
  float res = acc[0];
  if (a.bias) res += a.bias[(long)g * a.biasg + nn];
  a.out[(long)g * a.outg + (long)bo * a.N + nn] = res;
}

__global__ __launch_bounds__(1024) void init_control_kernel(const float* ci, float* control) {
  control[blockIdx.x * 1024 + threadIdx.x] = ci[0];
}

// ri_w [1024, 2048] -> ri_wT [2048, 1024]
__global__ __launch_bounds__(1024) void transpose_kernel(const float* in, float* out) {
  __shared__ float t[32][33];
  int j0 = blockIdx.x * 32;
  int d0 = blockIdx.y * 32;
  int tx = threadIdx.x, ty = threadIdx.y;
  t[ty][tx] = in[(long)(d0 + ty) * 2048 + j0 + tx];
  __syncthreads();
  out[(long)(j0 + ty) * 1024 + d0 + tx] = t[tx][ty];
}

// Hetero fusion, 3 roles over 160 blocks x 1024 thr:
//  [0,64):   ga gemm (mem_p = mo @ rm_w.T + rm_b), 16 cols/block
//  [64,128): gb gemm (memp2 = mo @ wm_w[:,D:].T + wm_b), 16 cols/block
//  [128,160): ctrl-att (P2), one block per batch row.
__global__ __launch_bounds__(1024) void ctrl_g2_kernel(GemmArgs ga, GemmArgs gb,
                                                       const float* cq,
                                                       const float* context,
                                                       const float* ca_w,
                                                       float* control) {
  __shared__ float smem[32 * 512];  // 64 KB
  const int bx = blockIdx.x;
  const int t = threadIdx.x;
  const int wave = t >> 6, lane = t & 63;

  if (bx < 128) {
    // ---- GEMM role: gemm32 pattern at 1024 thr / 16 cols ----
    const GemmArgs& g2 = (bx < 64) ? ga : gb;
    const int nb = (bx < 64) ? bx : bx - 64;
    const float* X1 = g2.X1;
    const int C = g2.c1;
    const int n = nb * 16 + wave;
    const float* wrow = g2.W + (long)n * g2.ldw;
    float acc[32];
#pragma unroll
    for (int b = 0; b < 32; b++) acc[b] = 0.f;
    for (int c0 = 0; c0 < C; c0 += 512) {
      __syncthreads();
#pragma unroll
      for (int i = 0; i < 4; i++) {
        int idx = t + 1024 * i;  // 0..4095 float4 slots
        int b = idx >> 7, c4 = idx & 127;
        *(float4*)(smem + b * 512 + c4 * 4) =
            *(const float4*)(X1 + (long)b * C + c0 + c4 * 4);
      }
      __syncthreads();
#pragma unroll
      for (int i = 0; i < 2; i++) {
        int c = i * 256 + lane * 4;
        float4 wv = *(const float4*)(wrow + c0 + c);
#pragma unroll
        for (int b = 0; b < 32; b++) {
          float4 xv = *(const float4*)(smem + b * 512 + c);
          acc[b] += wv.x * xv.x + wv.y * xv.y + wv.z * xv.z + wv.w * xv.w;
        }
      }
    }
    float res = 0.f;
#pragma unroll
    for (int b = 0; b < 32; b++) {
      float v = acc[b];
#pragma unroll
      for (int off = 32; off; off >>= 1) v += __shfl_xor(v, off, 64);
      if (lane == b) res = v;
    }
    if (lane < 32) {
      float o = res;
      if (g2.bias) o += g2.bias[n];
      g2.out[(long)lane * g2.N + n] = o;
    }
  } else {
    // ---- P2 role: ctrl-att (scores, softmax, contract) for b = bx-128 ----
    const int b = bx - 128;
    float* u = smem;         // 1024
    float* sc = smem + 1024; // 128
    u[t] = cq[b * 1024 + t] * ca_w[t];
    __syncthreads();
    const float* ctx = context + (long)b * 128 * 1024;
#pragma unroll
    for (int i = 0; i < 8; i++) {
      int s2 = wave * 8 + i;  // 16 waves x 8 = 128 scores
      float v = 0.f;
#pragma unroll
      for (int c = 0; c < 16; c++) v += u[c * 64 + lane] * ctx[(long)s2 * 1024 + c * 64 + lane];
#pragma unroll
      for (int off = 32; off; off >>= 1) v += __shfl_xor(v, off, 64);
      if (lane == 0) sc[s2] = v;  // ca_b dropped (softmax-invariant)
    }
    __syncthreads();
    if (wave == 0) {
      float a0 = sc[lane], a1 = sc[lane + 64];
      float m = fmaxf(a0, a1);
#pragma unroll
      for (int off = 32; off; off >>= 1) m = fmaxf(m, __shfl_xor(m, off, 64));
      float e0 = expf(a0 - m), e1 = expf(a1 - m);
      float s2 = e0 + e1;
#pragma unroll
      for (int off = 32; off; off >>= 1) s2 += __shfl_xor(s2, off, 64);
      float inv = 1.f / s2;
      sc[lane] = e0 * inv;
      sc[lane + 64] = e1 * inv;
    }
    __syncthreads();
    float acc = 0.f;
    for (int s2 = 0; s2 < 128; s2++) acc += sc[s2] * ctx[(long)s2 * 1024 + t];
    control[b * 1024 + t] = acc;
  }
}

// r_att partials: partial[jc][b][k] = sum_{j in chunk jc} g[b,j]*knowledge[b,j,k]
__global__ __launch_bounds__(512) void ratt_kernel(const float* knowledge, const float* mem_p,
                                                   const float* h, float* partial) {
  int b = blockIdx.x, jc = blockIdx.y;
  int j0 = jc * 64;
  __shared__ float gl[64];
  if (threadIdx.x < 64) {
    int j = j0 + threadIdx.x;
    gl[threadIdx.x] = mem_p[b * 1024 + j] * h[b * 2048 + j] + h[b * 2048 + 1024 + j];
  }
  __syncthreads();
  int k = threadIdx.x;  // 512 threads <-> K=512
  const float* kb = knowledge + ((long)b * 1024 + j0) * 512 + k;
  float acc = 0.f;
#pragma unroll 8
  for (int jj = 0; jj < 64; jj++) acc += gl[jj] * kb[(long)jj * 512];
  partial[((long)jc * 32 + b) * 512 + k] = acc;
}

// softmax(r_att) + read[b,d] = sum_k a[k]*knowledge[b,d,k]
// block (b, dg): 256 thr, 128 d per block (4 waves x 32 d).
__global__ __launch_bounds__(256) void read_kernel(const float* partial, const float* knowledge,
                                                   float* readv) {
  int b = blockIdx.x, dg = blockIdx.y;
  __shared__ float aw[512];
  __shared__ float red[4];
  int tid = threadIdx.x;
  int wave = tid >> 6, lane = tid & 63;
  int k0 = tid * 2;
  float r0 = 0.f, r1 = 0.f;
#pragma unroll
  for (int p = 0; p < 16; p++) {
    const float* pp = partial + ((long)p * 32 + b) * 512;
    r0 += pp[k0];
    r1 += pp[k0 + 1];
  }
  float m = fmaxf(r0, r1);
#pragma unroll
  for (int off = 32; off; off >>= 1) m = fmaxf(m, __shfl_xor(m, off, 64));
  if (lane == 0) red[wave] = m;
  __syncthreads();
  m = fmaxf(fmaxf(red[0], red[1]), fmaxf(red[2], red[3]));
  __syncthreads();  // all reads of red done before rewrite
  float e0 = expf(r0 - m), e1 = expf(r1 - m);
  float s2 = e0 + e1;
#pragma unroll
  for (int off = 32; off; off >>= 1) s2 += __shfl_xor(s2, off, 64);
  if (lane == 0) red[wave] = s2;
  __syncthreads();
  s2 = red[0] + red[1] + red[2] + red[3];
  float inv = 1.f / s2;
  aw[k0] = e0 * inv;
  aw[k0 + 1] = e1 * inv;
  __syncthreads();
  int d0 = dg * 128 + wave * 32;  // 4 waves x 32 d each
  float acc[32];
#pragma unroll
  for (int i = 0; i < 32; i++) acc[i] = 0.f;
  const float* kb = knowledge + ((long)b * 1024 + d0) * 512;
#pragma unroll
  for (int kc = 0; kc < 8; kc++) {
    int kk = kc * 64 + lane;
    float av = aw[kk];
#pragma unroll
    for (int dd = 0; dd < 32; dd++) acc[dd] += av * kb[(long)dd * 512 + kk];
  }
#pragma unroll
  for (int dd = 0; dd < 32; dd++) {
    float v = acc[dd];
#pragma unroll
    for (int off = 32; off; off >>= 1) v += __shfl_xor(v, off, 64);
    if (lane == (dd & 63)) acc[dd] = v;  // keep on its lane
  }
  // lane dd holds total for d0+dd in acc[dd]; write 32 outputs per wave
  if (lane < 32) readv[b * 1024 + d0 + lane] = acc[lane];
}

static inline void launch_gemm_wide(const float* X1, long x1g, int c1,
                                    const float* W, int ldw, long wg,
                                    const float* bias, long biasg,
                                    float* out, long outg, int N, int G,
                                    hipStream_t stream) {
  GemmArgs a{X1, x1g, nullptr, 0, c1, 0, W, ldw, wg, bias, biasg,
             nullptr, 0, nullptr, out, outg, N};
  gemm_wide_kernel<<<dim3(N / 16, G), 512, 0, stream>>>(a);
}

extern "C" void kernel_launch(void* const* d_in, const int* in_sizes, int n_in,
                              void* d_out, int out_size, void* d_ws, size_t ws_size,
                              hipStream_t stream) {
  const float* context      = (const float*)d_in[0];
  const float* question     = (const float*)d_in[1];
  const float* knowledge    = (const float*)d_in[2];
  const float* control_init = (const float*)d_in[3];
  const float* pa_w = (const float*)d_in[4];
  const float* pa_b = (const float*)d_in[5];
  const float* cq_w = (const float*)d_in[6];
  const float* cq_b = (const float*)d_in[7];
  const float* ca_w = (const float*)d_in[8];
  // d_in[9] ca_b: softmax-invariant, dropped
  const float* rm_w = (const float*)d_in[10];
  const float* rm_b = (const float*)d_in[11];
  const float* ri_w = (const float*)d_in[12];
  // d_in[13] ri_b: softmax-invariant, dropped
  const float* ra_w = (const float*)d_in[14];
  // d_in[15] ra_b: softmax-invariant, dropped
  const float* wm_w = (const float*)d_in[16];
  const float* wm_b = (const float*)d_in[17];
  float* out = (float*)d_out;

  float* p = (float*)d_ws;
  float* q_pa_all = p; p += NSTEP * 32 * 1024;
  float* qc_all   = p; p += NSTEP * 32 * 1024;
  float* ri_wT    = p; p += 2048 * 1024;
  float* control  = p; p += 32 * 1024;
  float* mem0     = p; p += 32 * 1024;
  float* mem1     = p; p += 32 * 1024;
  float* cq       = p; p += 32 * 1024;
  float* mem_p    = p; p += 32 * 1024;
  float* memp2    = p; p += 32 * 1024;
  float* h        = p; p += 32 * 2048;
  float* partial  = p; p += 16 * 32 * 512;
  float* readv    = p; p += 32 * 1024;

  init_control_kernel<<<32, 1024, 0, stream>>>(control_init, control);
  transpose_kernel<<<dim3(64, 32), dim3(32, 32), 0, stream>>>(ri_w, ri_wT);
  // q_pa_all[s] = question @ pa_w[s].T + pa_b[s]   (96 MB W stream)
  launch_gemm_wide(question, 0, 2048, pa_w, 2048, 1024L * 2048,
                   pa_b, 1024, q_pa_all, 32 * 1024, 1024, NSTEP, stream);
  hipMemcpyAsync(mem0, q_pa_all, 32 * 1024 * sizeof(float), hipMemcpyDeviceToDevice, stream);
  // qc_all[s] = q_pa_all[s] @ cq_w[:, D:].T   (hoisted out of the loop)
  launch_gemm_wide(q_pa_all, 32 * 1024, 1024, cq_w + 1024, 2048, 0,
                   nullptr, 0, qc_all, 32 * 1024, 1024, NSTEP, stream);

  // G1(0): cq = control @ cq_w[:, :D].T + qc_all[0] + cq_b
  {
    GemmArgs g1{control, 0, nullptr, 0, 1024, 0, cq_w, 2048, 0,
                cq_b, 0, qc_all, 0, nullptr, cq, 0, 1024};
    gemm32_kernel<<<256, 256, 0, stream>>>(g1);
  }

  float* mems[2] = {mem0, mem1};
  for (int s = 0; s < NSTEP; s++) {
    float* mo = mems[s & 1];
    float* mn = (s == NSTEP - 1) ? out : mems[(s + 1) & 1];

    // D_alpha: P2(s) || G2(s) [mem_p] || G2b(s) [memp2 = mo@wm_w2.T + wm_b]
    {
      GemmArgs ga{mo, 0, nullptr, 0, 1024, 0, rm_w, 1024, 0,
                  rm_b, 0, nullptr, 0, nullptr, mem_p, 0, 1024};
      GemmArgs gb{mo, 0, nullptr, 0, 1024, 0, wm_w + 1024, 2048, 0,
                  wm_b, 0, nullptr, 0, nullptr, memp2, 0, 1024};
      ctrl_g2_kernel<<<160, 1024, 0, stream>>>(ga, gb, cq, context, ca_w, control);
    }

    // D_beta: G3(s) [h = (control*ra_w) @ ri_wT.T] || G1(s+1) [next cq]
    {
      GemmArgs g3{control, 0, nullptr, 0, 1024, 0, ri_wT, 1024, 0,
                  nullptr, 0, nullptr, 0, ra_w, h, 0, 2048};
      if (s < NSTEP - 1) {
        GemmArgs g1{control, 0, nullptr, 0, 1024, 0, cq_w, 2048, 0,
                    cq_b, 0, qc_all + (long)(s + 1) * 32 * 1024, 0, nullptr,
                    cq, 0, 1024};
        gemm32_dual_kernel<<<768, 256, 0, stream>>>(g3, g1, 512);
      } else {
        gemm32_kernel<<<512, 256, 0, stream>>>(g3);
      }
    }

    // D_gamma: r_att partials
    ratt_kernel<<<dim3(32, 16), 512, 0, stream>>>(knowledge, mem_p, h, partial);
    // D_delta: softmax + read (128 d per block)
    read_kernel<<<dim3(32, 8), 256, 0, stream>>>(partial, knowledge, readv);
    // D_eps: new_memory = readv @ wm_w[:, :D].T + memp2   (C=1024)
    {
      GemmArgs g6{readv, 0, nullptr, 0, 1024, 0, wm_w, 2048, 0,
                  nullptr, 0, memp2, 0, nullptr, mn, 0, 1024};
      gemm32_kernel<<<256, 256, 0, stream>>>(g6);
    }
  }
}